// Round 3
// baseline (67.632 us; speedup 1.0000x reference)
//
#include <hip/hip_runtime.h>
#include <math.h>

// out (32,64,16,2048) f32 = one_hot(ascending-sorted top-16 indices of logits+gn).
// Forward value of stop_gradient(hard-soft)+soft == hard exactly (0) / ~1ulp (1).
//
// Strategy: (1) hipMemsetAsync zeroes the whole 256 MB output at pure-fill
// bandwidth (~7 TB/s measured on this chip for the rocclr fill kernel);
// (2) a light one-wave-per-row kernel computes the top-16 and scatters just
// the 32768 ones. Stream order guarantees fill-before-scatter.
#define K_SEL   16
#define VOCAB   2048
#define NROWS   2048   // BS(32) * D0(64)

__global__ __launch_bounds__(64) void topk_scatter_ones_kernel(
    const float* __restrict__ logits,   // (64, 2048)
    const float* __restrict__ gn,       // (32, 64, 2048)
    float* __restrict__ out)            // (32, 64, 16, 2048), already zeroed
{
    const int row  = blockIdx.x;        // row = bs*64 + d0
    const int d0   = row & 63;
    const int lane = threadIdx.x;       // 0..63 (one wave)

    const float* grow = gn     + (size_t)row * VOCAB;
    const float* lrow = logits + (size_t)d0  * VOCAB;
    float*       orow = out    + (size_t)row * (K_SEL * VOCAB);

    // lane owns columns c = seg*256 + lane*4 + j, seg=0..7, j=0..3
    float v[32];
    #pragma unroll
    for (int seg = 0; seg < 8; ++seg) {
        const int c = seg * 256 + lane * 4;
        const float4 g = *reinterpret_cast<const float4*>(grow + c);
        const float4 l = *reinterpret_cast<const float4*>(lrow + c);
        v[seg * 4 + 0] = l.x + g.x;
        v[seg * 4 + 1] = l.y + g.y;
        v[seg * 4 + 2] = l.z + g.z;
        v[seg * 4 + 3] = l.w + g.w;
    }

    // local argmax; ascending scan + strict '>' keeps lowest index on ties
    float lv = v[0]; int ls = 0;
    #pragma unroll
    for (int i = 1; i < 32; ++i) { if (v[i] > lv) { lv = v[i]; ls = i; } }

    int sel[K_SEL];

    #pragma unroll
    for (int k = 0; k < K_SEL; ++k) {
        // wave argmax via 64-lane butterfly on (value desc, col asc)
        float bv = lv;
        int   bc = ((ls >> 2) << 8) + lane * 4 + (ls & 3);
        #pragma unroll
        for (int off = 1; off < 64; off <<= 1) {
            const float ov = __shfl_xor(bv, off);
            const int   oc = __shfl_xor(bc, off);
            if (ov > bv || (ov == bv && oc < bc)) { bv = ov; bc = oc; }
        }
        sel[k] = bc;  // wave-uniform after butterfly
        // owner lane knocks out the winner and rescans its local max
        if (lane == ((bc >> 2) & 63)) {
            const int s = (((bc >> 8) & 7) << 2) | (bc & 3);
            lv = -INFINITY; ls = 0;
            #pragma unroll
            for (int i = 0; i < 32; ++i) {
                if (i == s) v[i] = -INFINITY;
                if (v[i] > lv) { lv = v[i]; ls = i; }
            }
        }
    }

    // one-hot row for sel[k] is its ascending rank among the 16 (all distinct);
    // owner lane stores the single 1.0 (output is already zeroed by memset).
    #pragma unroll
    for (int k = 0; k < K_SEL; ++k) {
        int r = 0;
        #pragma unroll
        for (int j = 0; j < K_SEL; ++j) r += (sel[j] < sel[k]) ? 1 : 0;
        if (lane == ((sel[k] >> 2) & 63)) {
            orow[(size_t)r * VOCAB + sel[k]] = 1.0f;
        }
    }
}

extern "C" void kernel_launch(void* const* d_in, const int* in_sizes, int n_in,
                              void* d_out, int out_size, void* d_ws, size_t ws_size,
                              hipStream_t stream) {
    const float* logits = (const float*)d_in[0];   // 64*2048
    const float* gn     = (const float*)d_in[1];   // 32*64*2048
    float* out          = (float*)d_out;           // 32*64*16*2048

    // Phase 1: zero the entire output at pure-fill bandwidth (graph-capturable
    // async memset node; stream-ordered before the scatter kernel).
    hipMemsetAsync(out, 0, (size_t)out_size * sizeof(float), stream);

    // Phase 2: top-16 selection + scatter of the 32768 ones.
    hipLaunchKernelGGL(topk_scatter_ones_kernel, dim3(NROWS), dim3(64), 0, stream,
                       logits, gn, out);
}

// Round 4
// 59.826 us; speedup vs baseline: 1.1305x; 1.1305x over previous
//
#include <hip/hip_runtime.h>
#include <math.h>

// out (32,64,16,2048) f32 = one_hot(ascending-sorted top-16 indices of logits+gn).
// Forward value of stop_gradient(hard-soft)+soft == hard exactly (0) / ~1ulp (1).
//
// Single kernel, one wave per (bs,d0) row:
//   phase 1: top-16 selection fully in registers (64-lane butterflies, no LDS,
//            no __syncthreads -> no forced vmcnt drains).
//   phase 2: one-pass streaming write of the 128KB output chunk with the 1.0s
//            injected inline (no memset, no RMW scatter, every byte written once).
#define K_SEL   16
#define VOCAB   2048
#define NROWS   2048   // BS(32) * D0(64)

__global__ __launch_bounds__(64) void topk_onehot_kernel(
    const float* __restrict__ logits,   // (64, 2048)
    const float* __restrict__ gn,       // (32, 64, 2048)
    float* __restrict__ out)            // (32, 64, 16, 2048)
{
    const int row  = blockIdx.x;        // row = bs*64 + d0
    const int d0   = row & 63;
    const int lane = threadIdx.x;       // 0..63 (one wave)

    const float* grow = gn     + (size_t)row * VOCAB;
    const float* lrow = logits + (size_t)d0  * VOCAB;
    float*       orow = out    + (size_t)row * (K_SEL * VOCAB);

    // lane owns columns c = seg*256 + lane*4 + j, seg=0..7, j=0..3
    float v[32];
    #pragma unroll
    for (int seg = 0; seg < 8; ++seg) {
        const int c = seg * 256 + lane * 4;
        const float4 g = *reinterpret_cast<const float4*>(grow + c);
        const float4 l = *reinterpret_cast<const float4*>(lrow + c);
        v[seg * 4 + 0] = l.x + g.x;
        v[seg * 4 + 1] = l.y + g.y;
        v[seg * 4 + 2] = l.z + g.z;
        v[seg * 4 + 3] = l.w + g.w;
    }

    // local argmax; ascending scan + strict '>' keeps lowest index on ties
    float lv = v[0]; int ls = 0;
    #pragma unroll
    for (int i = 1; i < 32; ++i) { if (v[i] > lv) { lv = v[i]; ls = i; } }

    int sel[K_SEL];

    // 16 rounds of wave argmax on (value desc, col asc) = lax.top_k order
    #pragma unroll
    for (int k = 0; k < K_SEL; ++k) {
        float bv = lv;
        int   bc = ((ls >> 2) << 8) + lane * 4 + (ls & 3);
        #pragma unroll
        for (int off = 1; off < 64; off <<= 1) {
            const float ov = __shfl_xor(bv, off);
            const int   oc = __shfl_xor(bc, off);
            if (ov > bv || (ov == bv && oc < bc)) { bv = ov; bc = oc; }
        }
        sel[k] = bc;  // wave-uniform after butterfly
        // owner lane knocks out the winner and rescans its local max
        if (lane == ((bc >> 2) & 63)) {
            const int s = (((bc >> 8) & 7) << 2) | (bc & 3);
            lv = -INFINITY; ls = 0;
            #pragma unroll
            for (int i = 0; i < 32; ++i) {
                if (i == s) v[i] = -INFINITY;
                if (v[i] > lv) { lv = v[i]; ls = i; }
            }
        }
    }

    // one-pass streaming write: row rank(sel[k]) gets a single 1.0 at sel[k].
    // All quantities wave-uniform except the lane column offset -> coalesced.
    #pragma unroll
    for (int k = 0; k < K_SEL; ++k) {
        int r = 0;
        #pragma unroll
        for (int j = 0; j < K_SEL; ++j) r += (sel[j] < sel[k]) ? 1 : 0;
        const int one = sel[k];
        float* rbase = orow + (size_t)r * VOCAB;
        #pragma unroll
        for (int seg = 0; seg < 8; ++seg) {
            const int c = seg * 256 + lane * 4;
            float4 a;
            a.x = (c + 0 == one) ? 1.0f : 0.0f;
            a.y = (c + 1 == one) ? 1.0f : 0.0f;
            a.z = (c + 2 == one) ? 1.0f : 0.0f;
            a.w = (c + 3 == one) ? 1.0f : 0.0f;
            *reinterpret_cast<float4*>(rbase + c) = a;
        }
    }
}

extern "C" void kernel_launch(void* const* d_in, const int* in_sizes, int n_in,
                              void* d_out, int out_size, void* d_ws, size_t ws_size,
                              hipStream_t stream) {
    const float* logits = (const float*)d_in[0];   // 64*2048
    const float* gn     = (const float*)d_in[1];   // 32*64*2048
    float* out          = (float*)d_out;           // 32*64*16*2048

    hipLaunchKernelGGL(topk_onehot_kernel, dim3(NROWS), dim3(64), 0, stream,
                       logits, gn, out);
}